// Round 6
// baseline (225.580 us; speedup 1.0000x reference)
//
#include <hip/hip_runtime.h>

typedef __attribute__((ext_vector_type(8))) short short8;
typedef __attribute__((ext_vector_type(4))) float f32x4;

#define INF 4096

#define AS1 __attribute__((address_space(1)))
#define AS3 __attribute__((address_space(3)))

__device__ __forceinline__ unsigned short f2bf(float f) {
    unsigned int u = __float_as_uint(f);
    u += 0x7FFFu + ((u >> 16) & 1u);
    return (unsigned short)(u >> 16);
}

__device__ __forceinline__ void gl_lds16(const unsigned short* g, void* l) {
    __builtin_amdgcn_global_load_lds((const AS1 void*)g, (AS3 void*)l, 16, 0, 0);
}

// swizzle within a 16KB half-tile [128 rows][64 bf16] (128B rows):
// XOR byte bits {4,5,6} with row bits {0,1,2}. Involution (bits 7-9 untouched),
// 16B-preserving, spreads stride-128B fragment reads across the full 128B row.
__device__ __forceinline__ int swz7(int b) { return b ^ ((b >> 3) & 0x70); }
// 64B-row variant used by the fallback kernel (R4/R5-verified, 0 conflicts)
__device__ __forceinline__ int swz6(int b) { return b ^ ((b >> 3) & 0x30); }

#define BAR()   __builtin_amdgcn_s_barrier()
#define SB0()   __builtin_amdgcn_sched_barrier(0)
#define LGKM0() { asm volatile("s_waitcnt lgkmcnt(0)" ::: "memory"); __builtin_amdgcn_sched_barrier(0); }

// ---------------- prepass: fp32 -> bf16 for x and hw ----------------
__global__ __launch_bounds__(256)
void cvt_bf16(const float* __restrict__ x, const float* __restrict__ hw,
              unsigned short* __restrict__ xb, unsigned short* __restrict__ wb)
{
    const long long NX = 8192LL * 4096;
    const long long NW = 5LL * 16 * 256 * 256;
    const long long total8 = (NX + NW) / 8;
    for (long long i = (long long)blockIdx.x * 256 + threadIdx.x; i < total8;
         i += (long long)gridDim.x * 256) {
        long long e = i * 8;
        const float* src;
        unsigned short* dst;
        long long off;
        if (e < NX) { src = x;  dst = xb; off = e; }
        else        { src = hw; dst = wb; off = e - NX; }
        float4 f0 = *(const float4*)(src + off);
        float4 f1 = *(const float4*)(src + off + 4);
        ushort4 u0, u1;
        u0.x = f2bf(f0.x); u0.y = f2bf(f0.y); u0.z = f2bf(f0.z); u0.w = f2bf(f0.w);
        u1.x = f2bf(f1.x); u1.y = f2bf(f1.y); u1.z = f2bf(f1.z); u1.w = f2bf(f1.w);
        *(ushort4*)(dst + off)     = u0;
        *(ushort4*)(dst + off + 4) = u1;
    }
}

// ======== main GEMM: 256x256 tile, 8 waves, BK=64, 8-phase counted-vmcnt ========
// LDS map (byte): buf(kt&1)*65536 + region*16384, regions: 0=A-half0(rows 0-127),
// 1=A-half1, 2=B-half0(cols 0-127), 3=B-half1. Half-tile = [128][64]bf16, rows
// 128B, swz7-swizzled. Staged 1 half/phase; destination safety: each region's
// ds_reads are issued >=1 phase before the stage and fenced by the intervening
// closing barrier. vmcnt(2) at P3 gates buf1 tile; at P7 gates next buf0 tile.
__global__ __launch_bounds__(512, 2)
void hcl_gemm8p(const unsigned short* __restrict__ xb,
                const unsigned short* __restrict__ wb,
                const float* __restrict__ hb,
                float* __restrict__ out)
{
    extern __shared__ char lds[];   // 131072

    const int tid  = threadIdx.x;       // 0..511
    const int lane = tid & 63;
    const int wave = tid >> 6;          // 0..7
    const int wr   = wave >> 2;         // 0..1  m-half
    const int wcn  = wave & 3;          // 0..3  n-quarter
    const int ln15 = lane & 15;
    const int hi   = lane >> 4;

    const int bm0 = blockIdx.x * 256;
    const int p   = blockIdx.y;

    // fragment byte offsets within a buffer (ks=0; ks=1 differs by ^64:
    // k-bit6 is pre-swz 0 and swz7 leaves bit6's source bits 7-9 unchanged)
    int offA[8], offB[4];
    #pragma unroll
    for (int mf = 0; mf < 8; ++mf)
        offA[mf] = wr * 16384 + swz7((mf * 16 + ln15) * 128 + hi * 16);
    #pragma unroll
    for (int nf = 0; nf < 4; ++nf)
        offB[nf] = 32768 + (wcn >> 1) * 16384 +
                   swz7(((wcn & 1) * 64 + nf * 16 + ln15) * 128 + hi * 16);

    // staging source geometry: inst j writes phys = j*8192 + tid*16 (linear),
    // so global source = logical swz7(phys)
    int srow[2], skcol[2];
    #pragma unroll
    for (int j = 0; j < 2; ++j) {
        int L = swz7(j * 8192 + tid * 16);
        srow[j]  = L >> 7;
        skcol[j] = (L & 127) >> 1;
    }

    f32x4 acc[8][4] = {};

    auto STAGE = [&](int kt, int reg) {   // reg: 0=A0,1=A1,2=B0,3=B1
        if (kt >= 20) return;
        const int t  = kt >> 2;
        const int s  = p ^ ((1 << t) >> 1);
        const int k0 = (kt & 3) * 64;
        char* dst = lds + (kt & 1) * 65536 + reg * 16384 + tid * 16;
        if (reg < 2) {
            const unsigned short* g = xb + (size_t)(bm0 + reg * 128) * INF + s * 256 + k0;
            gl_lds16(g + (size_t)srow[0] * INF + skcol[0], dst);
            gl_lds16(g + (size_t)srow[1] * INF + skcol[1], dst + 8192);
        } else {
            const unsigned short* g = wb + ((size_t)(t * 16 + s) << 16) + (reg - 2) * 32768 + k0;
            gl_lds16(g + (size_t)srow[0] * 256 + skcol[0], dst);
            gl_lds16(g + (size_t)srow[1] * 256 + skcol[1], dst + 8192);
        }
    };

    short8 fa[8], fb[4];
    auto LDA = [&](int qm, int buf) {    // 8 reads: mf = qm*4..+3, ks 0,1
        const char* L = lds + buf * 65536;
        #pragma unroll
        for (int m = 0; m < 4; ++m) {
            fa[m * 2 + 0] = *(const short8*)(L + offA[qm * 4 + m]);
            fa[m * 2 + 1] = *(const short8*)(L + (offA[qm * 4 + m] ^ 64));
        }
    };
    auto LDB = [&](int qn, int buf) {    // 4 reads: nf = qn*2..+1, ks 0,1
        const char* L = lds + buf * 65536;
        #pragma unroll
        for (int n = 0; n < 2; ++n) {
            fb[n * 2 + 0] = *(const short8*)(L + offB[qn * 2 + n]);
            fb[n * 2 + 1] = *(const short8*)(L + (offB[qn * 2 + n] ^ 64));
        }
    };
    auto MM = [&](int qm, int qn) {      // 16 MFMA: one C-quadrant x K=64
        __builtin_amdgcn_s_setprio(1);
        #pragma unroll
        for (int m = 0; m < 4; ++m)
            #pragma unroll
            for (int n = 0; n < 2; ++n)
                #pragma unroll
                for (int ks = 0; ks < 2; ++ks)
                    acc[qm * 4 + m][qn * 2 + n] = __builtin_amdgcn_mfma_f32_16x16x32_bf16(
                        fa[m * 2 + ks], fb[n * 2 + ks], acc[qm * 4 + m][qn * 2 + n], 0, 0, 0);
        __builtin_amdgcn_s_setprio(0);
    };

    // prologue: T0 complete + T1.A0 (5 halves, 10 loads); vmcnt(2) -> T0 landed
    STAGE(0, 0); STAGE(0, 1); STAGE(0, 2); STAGE(0, 3); STAGE(1, 0);
    asm volatile("s_waitcnt vmcnt(2)" ::: "memory");
    BAR(); SB0();

    for (int i = 0; i < 10; ++i) {
        const int ktB = 2 * i + 1;      // buf1 tile this iter
        const int ktN = 2 * i + 2;      // next buf0 tile
        // P0: buf0 (qm0,qn0)            stage T_B.A1
        LDA(0, 0); LDB(0, 0); STAGE(ktB, 1);
        BAR(); LGKM0(); MM(0, 0); BAR(); SB0();
        // P1: buf0 (qm0,qn1)            stage T_B.B0
        LDB(1, 0); STAGE(ktB, 2);
        BAR(); LGKM0(); MM(0, 1); BAR(); SB0();
        // P2: buf0 (qm1,qn1)            stage T_B.B1
        LDA(1, 0); STAGE(ktB, 3);
        BAR(); LGKM0(); MM(1, 1); BAR(); SB0();
        // P3: buf0 (qm1,qn0)            stage T_N.A0 ; gate T_B complete
        LDB(0, 0); STAGE(ktN, 0);
        if (i < 9) { asm volatile("s_waitcnt vmcnt(2)" ::: "memory"); }
        else       { asm volatile("s_waitcnt vmcnt(0)" ::: "memory"); }
        BAR(); LGKM0(); MM(1, 0); BAR(); SB0();
        // P4: buf1 (qm0,qn0)            stage T_N.A1
        LDA(0, 1); LDB(0, 1); STAGE(ktN, 1);
        BAR(); LGKM0(); MM(0, 0); BAR(); SB0();
        // P5: buf1 (qm0,qn1)            stage T_N.B0
        LDB(1, 1); STAGE(ktN, 2);
        BAR(); LGKM0(); MM(0, 1); BAR(); SB0();
        // P6: buf1 (qm1,qn1)            stage T_N.B1
        LDA(1, 1); STAGE(ktN, 3);
        BAR(); LGKM0(); MM(1, 1); BAR(); SB0();
        // P7: buf1 (qm1,qn0)            stage T_{N+1}.A0 ; gate T_N complete
        LDB(0, 1); STAGE(ktN + 1, 0);
        if (i < 9) { asm volatile("s_waitcnt vmcnt(2)" ::: "memory"); }
        BAR(); LGKM0(); MM(1, 0); BAR(); SB0();
    }

    // epilogue: C/D layout col = lane&15, row = (lane>>4)*4 + r  [R4-verified]
    const int col0 = p * 256 + wcn * 64;
    #pragma unroll
    for (int nf = 0; nf < 4; ++nf) {
        const int col = col0 + nf * 16 + ln15;
        const float bias = hb[col];
        #pragma unroll
        for (int mf = 0; mf < 8; ++mf) {
            #pragma unroll
            for (int r = 0; r < 4; ++r) {
                const int row = bm0 + wr * 128 + mf * 16 + hi * 4 + r;
                out[(size_t)row * 4096 + col] = acc[mf][nf][r] + bias;
            }
        }
    }
}

// -------- fallback GEMM (R5, proven): 128x256 tile, 4 waves, 3-buffer --------
#define NKT4 40
#define BUFB4 24576
__global__ __launch_bounds__(256, 2)
void hcl_gemm4(const unsigned short* __restrict__ xb,
               const unsigned short* __restrict__ wb,
               const float* __restrict__ hb,
               float* __restrict__ out)
{
    extern __shared__ unsigned short lds4[];

    const int tid  = threadIdx.x;
    const int lane = tid & 63;
    const int wave = tid >> 6;
    const int ln15 = lane & 15;
    const int hi   = lane >> 4;

    const int bm0 = blockIdx.x * 128;
    const int p   = blockIdx.y;

    int rj[4], cj[4];
    #pragma unroll
    for (int j = 0; j < 4; ++j) {
        int g = swz6(j * 4096 + tid * 16);
        rj[j] = g >> 6;
        cj[j] = (g & 63) >> 1;
    }

    int offA[8], offB[4];
    #pragma unroll
    for (int mf = 0; mf < 8; ++mf)
        offA[mf] = swz6((mf * 16 + ln15) * 64 + hi * 16);
    #pragma unroll
    for (int nf = 0; nf < 4; ++nf)
        offB[nf] = swz6((wave * 64 + nf * 16 + ln15) * 64 + hi * 16);

    f32x4 acc[8][4] = {};

    auto STAGE = [&](int kt, int buf) {
        const int t = kt >> 3;
        const int s = p ^ ((1 << t) >> 1);
        const unsigned short* ga = xb + (size_t)bm0 * INF + s * 256 + (kt & 7) * 32;
        const unsigned short* gb = wb + ((size_t)(t * 16 + s) << 16) + (kt & 7) * 32;
        char* lb = (char*)lds4 + buf * BUFB4 + wave * 1024;
        gl_lds16(ga + (size_t)rj[0] * INF + cj[0], lb);
        gl_lds16(ga + (size_t)rj[1] * INF + cj[1], lb + 4096);
        gl_lds16(gb + (size_t)rj[0] * 256 + cj[0], lb + 8192);
        gl_lds16(gb + (size_t)rj[1] * 256 + cj[1], lb + 8192 + 4096);
        gl_lds16(gb + (size_t)rj[2] * 256 + cj[2], lb + 8192 + 8192);
        gl_lds16(gb + (size_t)rj[3] * 256 + cj[3], lb + 8192 + 12288);
    };

    auto COMPUTE = [&](int buf) {
        const char* LA = (const char*)lds4 + buf * BUFB4;
        const char* LB = LA + 8192;
        short8 fa[8], fb[4];
        #pragma unroll
        for (int nf = 0; nf < 4; ++nf) fb[nf] = *(const short8*)(LB + offB[nf]);
        #pragma unroll
        for (int mf = 0; mf < 8; ++mf) fa[mf] = *(const short8*)(LA + offA[mf]);
        __builtin_amdgcn_s_setprio(1);
        #pragma unroll
        for (int mf = 0; mf < 8; ++mf)
            #pragma unroll
            for (int nf = 0; nf < 4; ++nf)
                acc[mf][nf] = __builtin_amdgcn_mfma_f32_16x16x32_bf16(
                    fa[mf], fb[nf], acc[mf][nf], 0, 0, 0);
        __builtin_amdgcn_s_setprio(0);
    };

    STAGE(0, 0);
    STAGE(1, 1);
    for (int kt = 0; kt < NKT4 - 2; ++kt) {
        STAGE(kt + 2, (kt + 2) % 3);
        asm volatile("s_waitcnt vmcnt(12)" ::: "memory");
        BAR(); SB0();
        COMPUTE(kt % 3);
        BAR(); SB0();
    }
    asm volatile("s_waitcnt vmcnt(6)" ::: "memory");
    BAR(); SB0();
    COMPUTE((NKT4 - 2) % 3);
    BAR(); SB0();
    asm volatile("s_waitcnt vmcnt(0)" ::: "memory");
    BAR(); SB0();
    COMPUTE((NKT4 - 1) % 3);

    const int col0 = p * 256 + wave * 64;
    #pragma unroll
    for (int nf = 0; nf < 4; ++nf) {
        const int col = col0 + nf * 16 + ln15;
        const float bias = hb[col];
        #pragma unroll
        for (int mf = 0; mf < 8; ++mf) {
            #pragma unroll
            for (int r = 0; r < 4; ++r) {
                const int row = bm0 + mf * 16 + hi * 4 + r;
                out[(size_t)row * 4096 + col] = acc[mf][nf][r] + bias;
            }
        }
    }
}

// ---------------- fallback (fused) if ws too small ----------------
__global__ __launch_bounds__(256)
void hcl_mfma_fused(const float* __restrict__ x,
                    const float* __restrict__ hw,
                    const float* __restrict__ hb,
                    float* __restrict__ out)
{
    __shared__ unsigned short As[128][32];
    __shared__ unsigned short Bs[128][32];

    const int tid  = threadIdx.x;
    const int lane = tid & 63;
    const int wave = tid >> 6;
    const int wr   = wave >> 1, wc = wave & 1;

    const int bm0 = blockIdx.x * 128;
    const int p   = blockIdx.y >> 1;
    const int nh  = blockIdx.y & 1;

    f32x4 acc[4][4] = {};

    const int srow = tid >> 3;
    const int scol = (tid & 7) * 4;

    #pragma unroll
    for (int t = 0; t < 5; ++t) {
        const int mask = (t == 0) ? 0 : (1 << (t - 1));
        const int s = p ^ mask;
        const float* xchunk = x  + (size_t)bm0 * INF + s * 256;
        const float* wchunk = hw + ((size_t)(t * 16 + s) * 256 + nh * 128) * 256;

        for (int k8 = 0; k8 < 8; ++k8) {
            const int kc = k8 * 32;
            #pragma unroll
            for (int i = 0; i < 4; ++i) {
                const int row = i * 32 + srow;
                float4 fa = *(const float4*)(xchunk + (size_t)row * INF + kc + scol);
                float4 fb = *(const float4*)(wchunk + (size_t)row * 256 + kc + scol);
                ushort4 ua, ub;
                ua.x = f2bf(fa.x); ua.y = f2bf(fa.y);
                ua.z = f2bf(fa.z); ua.w = f2bf(fa.w);
                ub.x = f2bf(fb.x); ub.y = f2bf(fb.y);
                ub.z = f2bf(fb.z); ub.w = f2bf(fb.w);
                *(ushort4*)&As[row][scol] = ua;
                *(ushort4*)&Bs[row][scol] = ub;
            }
            __syncthreads();

            short8 a[4], b[4];
            #pragma unroll
            for (int mi = 0; mi < 4; ++mi)
                a[mi] = *(const short8*)&As[wr * 64 + mi * 16 + (lane & 15)][(lane >> 4) * 8];
            #pragma unroll
            for (int nj = 0; nj < 4; ++nj)
                b[nj] = *(const short8*)&Bs[wc * 64 + nj * 16 + (lane & 15)][(lane >> 4) * 8];

            #pragma unroll
            for (int mi = 0; mi < 4; ++mi)
                #pragma unroll
                for (int nj = 0; nj < 4; ++nj)
                    acc[mi][nj] = __builtin_amdgcn_mfma_f32_16x16x32_bf16(
                        a[mi], b[nj], acc[mi][nj], 0, 0, 0);

            __syncthreads();
        }
    }

    const int col0 = p * 256 + nh * 128 + wc * 64;
    #pragma unroll
    for (int nj = 0; nj < 4; ++nj) {
        const int col = col0 + nj * 16 + (lane & 15);
        const float bias = hb[col];
        #pragma unroll
        for (int mi = 0; mi < 4; ++mi) {
            #pragma unroll
            for (int r = 0; r < 4; ++r) {
                const int row = bm0 + wr * 64 + mi * 16 + (lane >> 4) * 4 + r;
                out[(size_t)row * 4096 + col] = acc[mi][nj][r] + bias;
            }
        }
    }
}

extern "C" void kernel_launch(void* const* d_in, const int* in_sizes, int n_in,
                              void* d_out, int out_size, void* d_ws, size_t ws_size,
                              hipStream_t stream) {
    const float* x  = (const float*)d_in[0];   // [8192, 4096]
    const float* hw = (const float*)d_in[1];   // [5, 16, 256, 256]
    const float* hb = (const float*)d_in[2];   // [4096]
    float* out = (float*)d_out;                // [8192, 4096]

    const size_t NX = 8192ull * 4096;
    const size_t NW = 5ull * 16 * 256 * 256;
    const size_t need = (NX + NW) * sizeof(unsigned short);

    if (ws_size >= need) {
        unsigned short* xb = (unsigned short*)d_ws;
        unsigned short* wb = xb + NX;
        cvt_bf16<<<2048, 256, 0, stream>>>(x, hw, xb, wb);
        hipError_t e = hipFuncSetAttribute((const void*)hcl_gemm8p,
                                           hipFuncAttributeMaxDynamicSharedMemorySize,
                                           131072);
        if (e == hipSuccess) {
            dim3 grid(8192 / 256, 16);
            hcl_gemm8p<<<grid, 512, 131072, stream>>>(xb, wb, hb, out);
        } else {
            dim3 grid(8192 / 128, 16);
            hcl_gemm4<<<grid, 256, 3 * BUFB4, stream>>>(xb, wb, hb, out);
        }
    } else {
        dim3 grid(8192 / 128, 32);
        hcl_mfma_fused<<<grid, 256, 0, stream>>>(x, hw, hb, out);
    }
}